// Round 9
// baseline (68.648 us; speedup 1.0000x reference)
//
#include <hip/hip_runtime.h>
#include <math.h>

#define NQ 900   // queries (columns m)
#define NT 64    // targets (rows n)
#define NC 1203  // classes
#define BS 32    // batch
#define NCH 15   // 15 chunks of 64 columns cover 900 (chunk 14: lanes 0..3)
#define QB 15    // q-blocks of 64 per batch (14 full + one of 4)
#define FLAG_MAGIC 0xC0FFEE12AB34CD56ull

// ---------------------------------------------------------------------------
// Cross-lane helpers
// ---------------------------------------------------------------------------
__device__ __forceinline__ unsigned long long umin64(unsigned long long a,
                                                     unsigned long long b) {
    return a < b ? a : b;
}

__device__ __forceinline__ unsigned long long rl_u64(unsigned long long x, int l) {
    int lo = __builtin_amdgcn_readlane((int)(unsigned)x, l);
    int hi = __builtin_amdgcn_readlane((int)(x >> 32), l);
    return ((unsigned long long)(unsigned)hi << 32) | (unsigned)lo;
}

template <int CTRL>
__device__ __forceinline__ unsigned long long dpp_u64(unsigned long long k) {
    int lo = (int)(unsigned)k, hi = (int)(k >> 32);
    int nlo = __builtin_amdgcn_update_dpp(lo, lo, CTRL, 0xF, 0xF, false);
    int nhi = __builtin_amdgcn_update_dpp(hi, hi, CTRL, 0xF, 0xF, false);
    return ((unsigned long long)(unsigned)nhi << 32) | (unsigned)nlo;
}

// monotonic f64 -> u64 key (order-preserving)
__device__ __forceinline__ unsigned long long f64key(double d) {
    unsigned long long u = (unsigned long long)__double_as_longlong(d);
    return u ^ ((unsigned long long)((long long)u >> 63) | 0x8000000000000000ull);
}

// monotonic f32 -> u32 key
__device__ __forceinline__ unsigned f32key(float f) {
    unsigned u = (unsigned)__float_as_int(f);
    return u ^ ((unsigned)((int)u >> 31) | 0x80000000u);
}

// ---------------------------------------------------------------------------
// Fused kernel. Producer: block (b,qblk) computes its softmax/cost tile +
// per-block row-min keys (identical math to passing round 7), then signals
// via agent-scope release flag. Consumer: WAVE 0 ONLY of the qblk==14 block
// waits on the 14 peers and runs the round-7-validated single-wave JV solver
// (no __syncthreads in the solver path; waves 1-7 exit after the producer
// phase, fixing round 8's redundant-wave RMW races on u[]/p[]).
// ---------------------------------------------------------------------------
__global__ __launch_bounds__(512) void fused_kernel(
    const float* __restrict__ pred, const int* __restrict__ tgt,
    float* __restrict__ cost, unsigned long long* __restrict__ part,
    unsigned long long* __restrict__ flag, int* __restrict__ out)
{
    const int blk  = blockIdx.x;
    const int b    = blk / QB, qblk = blk % QB;
    const int wave = threadIdx.x >> 6, lane = threadIdx.x & 63;
    const int qcnt = (qblk == QB - 1) ? (NQ - 64 * (QB - 1)) : 64;   // 4 or 64

    __shared__ float  tile[64][65];
    __shared__ double u[NT + 1];
    __shared__ double deltas[NT + 8];
    __shared__ int    p[NQ + 1];
    __shared__ int    way[NQ + 1];

    // ---------------- producer: softmax + cost tile + row-min key ---------
    {
        int lab = tgt[b * NT + lane];                 // lane = target t
        for (int qloc = wave; qloc < qcnt; qloc += 8) {
            int q = qblk * 64 + qloc;
            const float* rp = pred + ((size_t)b * NQ + q) * NC;

            float xl = rp[lab];                       // issue gather early
            float s = 0.0f;
#pragma unroll
            for (int k = 0; k < 19; ++k) {
                int idx = lane + (k << 6);
                if (idx < NC) s += __expf(rp[idx]);
            }
#pragma unroll
            for (int off = 32; off > 0; off >>= 1)
                s += __shfl_xor(s, off);

            tile[lane][qloc] = -(__expf(xl) / s);     // lane = target t
        }
    }
    __syncthreads();

    for (int t = wave; t < NT; t += 8) {
        float v = (lane < qcnt) ? tile[t][lane] : INFINITY;
        int q = qblk * 64 + lane;
        if (lane < qcnt)
            cost[((size_t)b * NT + t) * NQ + q] = v;

        unsigned long long key =
            ((unsigned long long)f32key(v) << 32) | (unsigned)q;
        key = umin64(key, dpp_u64<0xB1>(key));    // quad_perm [1,0,3,2]
        key = umin64(key, dpp_u64<0x4E>(key));    // quad_perm [2,3,0,1]
        key = umin64(key, dpp_u64<0x124>(key));   // row_ror:4
        key = umin64(key, dpp_u64<0x128>(key));   // row_ror:8
        unsigned long long kmin =
            umin64(umin64(rl_u64(key, 0),  rl_u64(key, 16)),
                   umin64(rl_u64(key, 32), rl_u64(key, 48)));
        if (lane == 0) part[((size_t)b * NT + t) * QB + qblk] = kmin;
    }
    __syncthreads();   // all waves' stores issued before the release

    if (threadIdx.x == 0) {
        __threadfence();                              // agent-scope release
        __hip_atomic_store(&flag[b * QB + qblk], FLAG_MAGIC,
                           __ATOMIC_RELEASE, __HIP_MEMORY_SCOPE_AGENT);
    }
    if (qblk != QB - 1 || wave != 0) return;   // consumer = wave 0 of last blk

    // ---------------- consumer: wait for the 14 peer tiles ----------------
    for (;;) {
        unsigned long long f = (lane < QB - 1)
            ? __hip_atomic_load(&flag[b * QB + lane], __ATOMIC_ACQUIRE,
                                __HIP_MEMORY_SCOPE_AGENT)
            : FLAG_MAGIC;
        if (__all(f == FLAG_MAGIC)) break;
        __builtin_amdgcn_s_sleep(16);
    }
    __threadfence();                                  // acquire: invalidate caches

    // -------- exact JV, SINGLE WAVE (round-7 code, barriers dropped) ------
    for (int j = lane; j <= NQ; j += 64) p[j] = 0;

    double vv[NCH];
    double minv[NCH];
    float  rA[NCH];
    int    wy[NCH];
    int    sj[NCH];

#pragma unroll
    for (int c = 0; c < NCH; ++c) vv[c] = 0.0;

    const unsigned invalid = (lane < 4) ? 0u : (1u << 14);
    const float* a = cost + (size_t)b * NT * NQ;

#define GLOAD_TO(DST, I0)                                             \
    do {                                                              \
        const float* ar_ = a + (size_t)((I0) - 1) * NQ;               \
        _Pragma("unroll")                                             \
        for (int c_ = 0; c_ < 14; ++c_) DST[c_] = ar_[c_ * 64 + lane];\
        DST[14] = (lane < 4) ? ar_[896 + lane] : 0.0f;                \
    } while (0)

    // ---- Phase A: reduce parts, greedy init ----
    const unsigned long long* pp = part + ((size_t)b * NT + lane) * QB;
    unsigned long long rm = pp[0];
#pragma unroll
    for (int k = 1; k < QB; ++k) rm = umin64(rm, pp[k]);

    unsigned k32 = (unsigned)(rm >> 32);
    unsigned ubits = (k32 & 0x80000000u) ? (k32 ^ 0x80000000u) : ~k32;  // inverse f32key
    float mval = __int_as_float((int)ubits);
    int col = (int)(rm & 0xFFFFFFFFu) + 1;           // 1-based argmin column

    u[lane + 1] = (double)mval;                      // u[t] = rowmin (JV-legal)
    if (lane == 0) u[0] = 0.0;

    int dup = 0;
    for (int t2 = 0; t2 < NT; ++t2) {
        int c2 = __shfl(col, t2);
        if (t2 < lane && c2 == col) dup = 1;         // earlier row took my column
    }
    bool m0 = !dup;
    if (m0) p[col] = lane + 1;                       // matched cols are distinct
    unsigned long long matched_rows = __ballot(m0);

    // ---- Phase B: Dijkstra for unmatched rows ----
    unsigned long long um = ~matched_rows;
    while (um) {
        int i = __ffsll((long long)um);              // row 1..64
        um &= um - 1;

        GLOAD_TO(rA, i);
        if (lane == 0) p[0] = i;
#pragma unroll
        for (int c = 0; c < NCH; ++c) { minv[c] = INFINITY; wy[c] = 0; }
        unsigned joined = 0;
        double pdelta = 0.0;
        double ui0 = u[i];
        int j0 = 0, K = 0;

        for (int k = 1; k <= NT + 2; ++k) {
            K = k;
            unsigned fm = ~(joined | invalid);
            double tv[16]; int tj[16];
#pragma unroll
            for (int c = 0; c < NCH; ++c) {
                double m   = minv[c] - pdelta;           // deferred subtract
                double cur = (double)rA[c] - ui0 - vv[c];
                bool live = (fm >> c) & 1;
                if (live && (cur < m)) wy[c] = j0;
                if (cur < m) m = cur;                    // joined drift never read
                minv[c] = m;
                tv[c] = live ? m : INFINITY;
                tj[c] = 1 + c * 64 + lane;
            }
            tv[15] = INFINITY; tj[15] = 0x7fffffff;
            // ordered adjacent-pair tree (strict < keeps smaller j on ties)
#pragma unroll
            for (int w = 16; w > 1; w >>= 1)
#pragma unroll
                for (int t = 0; t < (w >> 1); ++t) {
                    if (tv[2 * t + 1] < tv[2 * t]) { tv[t] = tv[2 * t + 1]; tj[t] = tj[2 * t + 1]; }
                    else                           { tv[t] = tv[2 * t];     tj[t] = tj[2 * t]; }
                }
            double bestv = tv[0];
            int    bestj = tj[0];

            // speculative p/u reads (latency hidden under the reduce)
            int bjc = (bestj <= NQ) ? bestj : 0;
            int ppj_spec = p[bjc];
            double u_spec = u[ppj_spec];

            unsigned long long key = f64key(bestv);
            unsigned long long kk = key;
            kk = umin64(kk, dpp_u64<0xB1>(kk));
            kk = umin64(kk, dpp_u64<0x4E>(kk));
            kk = umin64(kk, dpp_u64<0x124>(kk));
            kk = umin64(kk, dpp_u64<0x128>(kk));
            unsigned long long kmin =
                umin64(umin64(rl_u64(kk, 0),  rl_u64(kk, 16)),
                       umin64(rl_u64(kk, 32), rl_u64(kk, 48)));
            unsigned long long mask = __ballot(key == kmin);
            int wl = __ffsll((long long)mask) - 1;
            int j1 = __builtin_amdgcn_readlane(bestj, wl);
            int lane1 = wl;
            if (__popcll(mask) > 1) {                    // exact tie: smallest j
                unsigned long long mm = mask & (mask - 1);
                while (mm) {
                    int l2 = __ffsll((long long)mm) - 1;
                    int j2 = __builtin_amdgcn_readlane(bestj, l2);
                    if (j2 < j1) { j1 = j2; lane1 = l2; }
                    mm &= mm - 1;
                }
            }
            double delta = __longlong_as_double(
                (long long)rl_u64((unsigned long long)__double_as_longlong(bestv), wl));

            if (lane == 0) deltas[k] = delta;
            pdelta = delta;

            int och = (j1 - 1) >> 6, oln = (j1 - 1) & 63;
#pragma unroll
            for (int c = 0; c < NCH; ++c)
                if (och == c && lane == oln) { joined |= (1u << c); sj[c] = k + 1; }

            int ppj1 = __builtin_amdgcn_readlane(ppj_spec, lane1);
            j0 = j1;
            if (ppj1 == 0) break;                        // augmenting path found

            ui0 = __longlong_as_double((long long)rl_u64(
                (unsigned long long)__double_as_longlong(u_spec), lane1));
            GLOAD_TO(rA, ppj1);
        }

        // ---- phase epilogue (single wave: LDS ops program-ordered) ----
#pragma unroll
        for (int c = 0; c < NCH; ++c) {
            int j = 1 + c * 64 + lane;
            if (j <= NQ) way[j] = wy[c];
        }

#pragma unroll
        for (int c = 0; c < NCH; ++c) {
            if (joined & (1u << c)) {
                int s = sj[c];
                if (s <= K) {
                    int j = 1 + c * 64 + lane;
                    double vacc = vv[c];
                    for (int k2 = s; k2 <= K; ++k2) vacc -= deltas[k2];
                    vv[c] = vacc;
                    int pj = p[j];                       // pre-augmentation p
                    double ua = u[pj];
                    for (int k2 = s; k2 <= K; ++k2) ua += deltas[k2];
                    u[pj] = ua;
                }
            }
        }
        if (lane == 0) {
            double ua = u[i];
            for (int k2 = 1; k2 <= K; ++k2) ua += deltas[k2];
            u[i] = ua;
        }

        if (lane == 0) {                                 // augment
            int jj = j0;
            for (int g = 0; g < NT + 4 && jj != 0; ++g) {
                int jn = way[jj];
                p[jj] = p[jn];
                jj = jn;
            }
        }
    }
#undef GLOAD_TO

    // ---- compaction ----
    int base_cnt = 0;
    for (int c = 0; c < NCH; ++c) {
        int j = 1 + c * 64 + lane;
        bool matched = (j <= NQ) && (p[j] != 0);
        unsigned long long mask = __ballot(matched);
        int rank = base_cnt + __popcll(mask & ((1ull << lane) - 1ull));
        if (matched) {
            out[b * NT + rank]           = j - 1;     // rows: query index
            out[BS * NT + b * NT + rank] = p[j] - 1;  // cols: target index
        }
        base_cnt += __popcll(mask);
    }
}

extern "C" void kernel_launch(void* const* d_in, const int* in_sizes, int n_in,
                              void* d_out, int out_size, void* d_ws, size_t ws_size,
                              hipStream_t stream) {
    const float* pred = (const float*)d_in[0];  // [32,900,1203] f32
    const int*   tgt  = (const int*)d_in[1];    // [32,64] int
    int*         out  = (int*)d_out;            // [2][32][64] int32

    char* ws = (char*)d_ws;
    float* cost = (float*)ws;                                      // 7,372,800 B
    unsigned long long* part =
        (unsigned long long*)(ws + (size_t)BS * NT * NQ * 4);      // 245,760 B
    unsigned long long* flag =
        (unsigned long long*)(ws + (size_t)BS * NT * NQ * 4
                                 + (size_t)BS * NT * QB * 8);      // 3,840 B

    fused_kernel<<<BS * QB, 512, 0, stream>>>(pred, tgt, cost, part, flag, out);
}

// Round 11
// 57.002 us; speedup vs baseline: 1.2043x; 1.2043x over previous
//
#include <hip/hip_runtime.h>
#include <math.h>

#define NQ 900   // queries (columns m)
#define NT 64    // targets (rows n)
#define NC 1203  // classes
#define BS 32    // batch
#define NCH 15   // 15 chunks of 64 columns cover 900 (chunk 14: lanes 0..3)
#define QB 15    // q-blocks of 64 per batch (14 full + one of 4)

// ---------------------------------------------------------------------------
// Cross-lane helpers
// ---------------------------------------------------------------------------
__device__ __forceinline__ unsigned long long umin64(unsigned long long a,
                                                     unsigned long long b) {
    return a < b ? a : b;
}

__device__ __forceinline__ unsigned long long rl_u64(unsigned long long x, int l) {
    int lo = __builtin_amdgcn_readlane((int)(unsigned)x, l);
    int hi = __builtin_amdgcn_readlane((int)(x >> 32), l);
    return ((unsigned long long)(unsigned)hi << 32) | (unsigned)lo;
}

template <int CTRL>
__device__ __forceinline__ unsigned long long dpp_u64(unsigned long long k) {
    int lo = (int)(unsigned)k, hi = (int)(k >> 32);
    int nlo = __builtin_amdgcn_update_dpp(lo, lo, CTRL, 0xF, 0xF, false);
    int nhi = __builtin_amdgcn_update_dpp(hi, hi, CTRL, 0xF, 0xF, false);
    return ((unsigned long long)(unsigned)nhi << 32) | (unsigned)nlo;
}

// monotonic f64 -> u64 key (order-preserving)
__device__ __forceinline__ unsigned long long f64key(double d) {
    unsigned long long u = (unsigned long long)__double_as_longlong(d);
    return u ^ ((unsigned long long)((long long)u >> 63) | 0x8000000000000000ull);
}

// monotonic f32 -> u32 key (order-preserving)
__device__ __forceinline__ unsigned f32key(float f) {
    unsigned u = (unsigned)__float_as_int(f);
    return u ^ ((unsigned)((int)u >> 31) | 0x80000000u);
}

// ---------------------------------------------------------------------------
// Kernel 1: block-tiled softmax + cost gather + per-block row-min keys.
// (byte-identical math to the round-7 PASSED kernel)
// ---------------------------------------------------------------------------
__global__ __launch_bounds__(512) void softmax_cost_kernel(
    const float* __restrict__ pred, const int* __restrict__ tgt,
    float* __restrict__ cost, unsigned long long* __restrict__ part)
{
    int b = blockIdx.x / QB, qblk = blockIdx.x % QB;
    int wave = threadIdx.x >> 6, lane = threadIdx.x & 63;
    int qcnt = (qblk == QB - 1) ? (NQ - 64 * (QB - 1)) : 64;   // 4 or 64

    __shared__ float tile[64][65];
    int lab = tgt[b * NT + lane];                 // lane = target t

    for (int qloc = wave; qloc < qcnt; qloc += 8) {
        int q = qblk * 64 + qloc;
        const float* rp = pred + ((size_t)b * NQ + q) * NC;

        float xl = rp[lab];                       // issue gather early
        float s = 0.0f;
#pragma unroll
        for (int k = 0; k < 19; ++k) {
            int idx = lane + (k << 6);
            if (idx < NC) s += __expf(rp[idx]);
        }
#pragma unroll
        for (int off = 32; off > 0; off >>= 1)
            s += __shfl_xor(s, off);

        tile[lane][qloc] = -(__expf(xl) / s);     // lane = target t
    }
    __syncthreads();

    // coalesced write + per-row block min (lane = q)
    for (int t = wave; t < NT; t += 8) {
        float v = (lane < qcnt) ? tile[t][lane] : INFINITY;
        int q = qblk * 64 + lane;
        if (lane < qcnt)
            cost[((size_t)b * NT + t) * NQ + q] = v;

        unsigned long long key =
            ((unsigned long long)f32key(v) << 32) | (unsigned)q;
        key = umin64(key, dpp_u64<0xB1>(key));    // quad_perm [1,0,3,2]
        key = umin64(key, dpp_u64<0x4E>(key));    // quad_perm [2,3,0,1]
        key = umin64(key, dpp_u64<0x124>(key));   // row_ror:4
        key = umin64(key, dpp_u64<0x128>(key));   // row_ror:8
        unsigned long long kmin =
            umin64(umin64(rl_u64(key, 0),  rl_u64(key, 16)),
                   umin64(rl_u64(key, 32), rl_u64(key, 48)));
        if (lane == 0) part[((size_t)b * NT + t) * QB + qblk] = kmin;
    }
}

// ---------------------------------------------------------------------------
// Kernel 2: exact JV. Waves 1-7: warm the local XCD L2 with the batch's
// 230 KB cost block (pure reads, asm sink), then exit. Wave 0: the round-9
// PASSED barrier-free single-wave f64 solver (shuffle dup-detect, deferred
// bit-exact dual replay).
// ---------------------------------------------------------------------------
__global__ __launch_bounds__(512) void jv_kernel(
    const float* __restrict__ cost,
    const unsigned long long* __restrict__ part, int* __restrict__ out)
{
    const int b    = blockIdx.x;
    const int wave = threadIdx.x >> 6;
    const int lane = threadIdx.x & 63;
    const float* a = cost + (size_t)b * NT * NQ;

    // ---------------- prefetch crew: warm local L2, then exit -------------
    if (wave != 0) {
        const float4* a4 = (const float4*)a;      // 14400 float4
        float acc = 0.0f;
        int base = (wave - 1) * 64 + lane;        // [0, 448)
        for (int g = 0; g < 5; ++g) {
            float4 v[8];
#pragma unroll
            for (int t = 0; t < 8; ++t) {
                int idx = base + g * 3584 + t * 448;
                v[t] = (idx < NT * NQ / 4) ? a4[idx] : make_float4(0, 0, 0, 0);
            }
#pragma unroll
            for (int t = 0; t < 8; ++t)
                acc += v[t].x + v[t].y + v[t].z + v[t].w;
        }
        asm volatile("" :: "v"(acc));             // sink (prevent DCE)
        return;
    }

    // -------- wave 0: single-wave exact JV (round-9 PASSED solver) --------
    __shared__ double u[NT + 1];
    __shared__ double deltas[NT + 8];
    __shared__ int    p[NQ + 1];
    __shared__ int    way[NQ + 1];

    for (int j = lane; j <= NQ; j += 64) p[j] = 0;

    double vv[NCH];
    double minv[NCH];
    float  rA[NCH];
    int    wy[NCH];
    int    sj[NCH];

#pragma unroll
    for (int c = 0; c < NCH; ++c) vv[c] = 0.0;

    const unsigned invalid = (lane < 4) ? 0u : (1u << 14);

#define GLOAD_TO(DST, I0)                                             \
    do {                                                              \
        const float* ar_ = a + (size_t)((I0) - 1) * NQ;               \
        _Pragma("unroll")                                             \
        for (int c_ = 0; c_ < 14; ++c_) DST[c_] = ar_[c_ * 64 + lane];\
        DST[14] = (lane < 4) ? ar_[896 + lane] : 0.0f;                \
    } while (0)

    // ---- Phase A: reduce parts, greedy init (shuffle dup-detect) ----
    const unsigned long long* pp = part + ((size_t)b * NT + lane) * QB;
    unsigned long long rm = pp[0];
#pragma unroll
    for (int k = 1; k < QB; ++k) rm = umin64(rm, pp[k]);

    unsigned k32 = (unsigned)(rm >> 32);
    unsigned ubits = (k32 & 0x80000000u) ? (k32 ^ 0x80000000u) : ~k32;  // inverse f32key
    float mval = __int_as_float((int)ubits);
    int col = (int)(rm & 0xFFFFFFFFu) + 1;           // 1-based argmin column

    u[lane + 1] = (double)mval;                      // u[t] = rowmin (JV-legal)
    if (lane == 0) u[0] = 0.0;

    int dup = 0;
    for (int t2 = 0; t2 < NT; ++t2) {
        int c2 = __shfl(col, t2);
        if (t2 < lane && c2 == col) dup = 1;         // earlier row took my column
    }
    bool m0 = !dup;
    if (m0) p[col] = lane + 1;                       // matched cols are distinct
    unsigned long long matched_rows = __ballot(m0);

    // ---- Phase B: Dijkstra for unmatched rows (f64, bit-exact replay) ----
    unsigned long long um = ~matched_rows;
    while (um) {
        int i = __ffsll((long long)um);              // row 1..64
        um &= um - 1;

        GLOAD_TO(rA, i);
        if (lane == 0) p[0] = i;
#pragma unroll
        for (int c = 0; c < NCH; ++c) { minv[c] = INFINITY; wy[c] = 0; }
        unsigned joined = 0;
        double pdelta = 0.0;
        double ui0 = u[i];
        int j0 = 0, K = 0;

        for (int k = 1; k <= NT + 2; ++k) {
            K = k;
            unsigned fm = ~(joined | invalid);
            double tv[16]; int tj[16];
#pragma unroll
            for (int c = 0; c < NCH; ++c) {
                double m   = minv[c] - pdelta;           // deferred subtract
                double cur = (double)rA[c] - ui0 - vv[c];
                bool live = (fm >> c) & 1;
                if (live && (cur < m)) wy[c] = j0;
                if (cur < m) m = cur;                    // joined drift never read
                minv[c] = m;
                tv[c] = live ? m : INFINITY;
                tj[c] = 1 + c * 64 + lane;
            }
            tv[15] = INFINITY; tj[15] = 0x7fffffff;
            // ordered adjacent-pair tree (strict < keeps smaller j on ties)
#pragma unroll
            for (int w = 16; w > 1; w >>= 1)
#pragma unroll
                for (int t = 0; t < (w >> 1); ++t) {
                    if (tv[2 * t + 1] < tv[2 * t]) { tv[t] = tv[2 * t + 1]; tj[t] = tj[2 * t + 1]; }
                    else                           { tv[t] = tv[2 * t];     tj[t] = tj[2 * t]; }
                }
            double bestv = tv[0];
            int    bestj = tj[0];

            // speculative p/u reads (latency hidden under the reduce)
            int bjc = (bestj <= NQ) ? bestj : 0;
            int ppj_spec = p[bjc];
            double u_spec = u[ppj_spec];

            unsigned long long key = f64key(bestv);
            unsigned long long kk = key;
            kk = umin64(kk, dpp_u64<0xB1>(kk));
            kk = umin64(kk, dpp_u64<0x4E>(kk));
            kk = umin64(kk, dpp_u64<0x124>(kk));
            kk = umin64(kk, dpp_u64<0x128>(kk));
            unsigned long long kmin =
                umin64(umin64(rl_u64(kk, 0),  rl_u64(kk, 16)),
                       umin64(rl_u64(kk, 32), rl_u64(kk, 48)));
            unsigned long long mask = __ballot(key == kmin);
            int wl = __ffsll((long long)mask) - 1;
            int j1 = __builtin_amdgcn_readlane(bestj, wl);
            int lane1 = wl;
            if (__popcll(mask) > 1) {                    // exact tie: smallest j
                unsigned long long mm = mask & (mask - 1);
                while (mm) {
                    int l2 = __ffsll((long long)mm) - 1;
                    int j2 = __builtin_amdgcn_readlane(bestj, l2);
                    if (j2 < j1) { j1 = j2; lane1 = l2; }
                    mm &= mm - 1;
                }
            }
            double delta = __longlong_as_double(
                (long long)rl_u64((unsigned long long)__double_as_longlong(bestv), wl));

            if (lane == 0) deltas[k] = delta;
            pdelta = delta;

            int och = (j1 - 1) >> 6, oln = (j1 - 1) & 63;
#pragma unroll
            for (int c = 0; c < NCH; ++c)
                if (och == c && lane == oln) { joined |= (1u << c); sj[c] = k + 1; }

            int ppj1 = __builtin_amdgcn_readlane(ppj_spec, lane1);
            j0 = j1;
            if (ppj1 == 0) break;                        // augmenting path found

            ui0 = __longlong_as_double((long long)rl_u64(
                (unsigned long long)__double_as_longlong(u_spec), lane1));
            GLOAD_TO(rA, ppj1);
        }

        // ---- phase epilogue (single wave: LDS ops program-ordered) ----
#pragma unroll
        for (int c = 0; c < NCH; ++c) {
            int j = 1 + c * 64 + lane;
            if (j <= NQ) way[j] = wy[c];
        }

#pragma unroll
        for (int c = 0; c < NCH; ++c) {
            if (joined & (1u << c)) {
                int s = sj[c];
                if (s <= K) {
                    int j = 1 + c * 64 + lane;
                    double vacc = vv[c];
                    for (int k2 = s; k2 <= K; ++k2) vacc -= deltas[k2];
                    vv[c] = vacc;
                    int pj = p[j];                       // pre-augmentation p
                    double ua = u[pj];
                    for (int k2 = s; k2 <= K; ++k2) ua += deltas[k2];
                    u[pj] = ua;
                }
            }
        }
        if (lane == 0) {
            double ua = u[i];
            for (int k2 = 1; k2 <= K; ++k2) ua += deltas[k2];
            u[i] = ua;
        }

        if (lane == 0) {                                 // augment
            int jj = j0;
            for (int g = 0; g < NT + 4 && jj != 0; ++g) {
                int jn = way[jj];
                p[jj] = p[jn];
                jj = jn;
            }
        }
    }
#undef GLOAD_TO

    // ---- compaction ----
    int base_cnt = 0;
    for (int c = 0; c < NCH; ++c) {
        int j = 1 + c * 64 + lane;
        bool matched = (j <= NQ) && (p[j] != 0);
        unsigned long long mask = __ballot(matched);
        int rank = base_cnt + __popcll(mask & ((1ull << lane) - 1ull));
        if (matched) {
            out[b * NT + rank]           = j - 1;     // rows: query index
            out[BS * NT + b * NT + rank] = p[j] - 1;  // cols: target index
        }
        base_cnt += __popcll(mask);
    }
}

extern "C" void kernel_launch(void* const* d_in, const int* in_sizes, int n_in,
                              void* d_out, int out_size, void* d_ws, size_t ws_size,
                              hipStream_t stream) {
    const float* pred = (const float*)d_in[0];  // [32,900,1203] f32
    const int*   tgt  = (const int*)d_in[1];    // [32,64] int
    int*         out  = (int*)d_out;            // [2][32][64] int32

    char* ws = (char*)d_ws;
    float* cost = (float*)ws;                                      // 7,372,800 B
    unsigned long long* part =
        (unsigned long long*)(ws + (size_t)BS * NT * NQ * 4);      // 245,760 B

    softmax_cost_kernel<<<BS * QB, 512, 0, stream>>>(pred, tgt, cost, part);
    jv_kernel<<<BS, 512, 0, stream>>>(cost, part, out);
}

// Round 13
// 56.456 us; speedup vs baseline: 1.2160x; 1.0097x over previous
//
#include <hip/hip_runtime.h>
#include <math.h>

#define NQ 900   // queries (columns m)
#define NT 64    // targets (rows n)
#define NC 1203  // classes
#define BS 32    // batch
#define NCH 15   // 15 chunks of 64 columns cover 900 (chunk 14: lanes 0..3)
#define QB 15    // q-blocks of 64 per batch (14 full + one of 4)

// ---------------------------------------------------------------------------
// Cross-lane helpers
// ---------------------------------------------------------------------------
__device__ __forceinline__ unsigned long long umin64(unsigned long long a,
                                                     unsigned long long b) {
    return a < b ? a : b;
}

__device__ __forceinline__ unsigned long long rl_u64(unsigned long long x, int l) {
    int lo = __builtin_amdgcn_readlane((int)(unsigned)x, l);
    int hi = __builtin_amdgcn_readlane((int)(x >> 32), l);
    return ((unsigned long long)(unsigned)hi << 32) | (unsigned)lo;
}

template <int CTRL>
__device__ __forceinline__ unsigned long long dpp_u64(unsigned long long k) {
    int lo = (int)(unsigned)k, hi = (int)(k >> 32);
    int nlo = __builtin_amdgcn_update_dpp(lo, lo, CTRL, 0xF, 0xF, false);
    int nhi = __builtin_amdgcn_update_dpp(hi, hi, CTRL, 0xF, 0xF, false);
    return ((unsigned long long)(unsigned)nhi << 32) | (unsigned)nlo;
}

template <int CTRL>
__device__ __forceinline__ float dpp_f32(float x) {
    return __int_as_float(__builtin_amdgcn_update_dpp(
        __float_as_int(x), __float_as_int(x), CTRL, 0xF, 0xF, false));
}

// fast wave-wide f32 sum: DPP 16-lane ladder + 4 readlanes (all lanes get total)
__device__ __forceinline__ float wave_sum(float s) {
    s += dpp_f32<0xB1>(s);    // quad_perm [1,0,3,2]
    s += dpp_f32<0x4E>(s);    // quad_perm [2,3,0,1]
    s += dpp_f32<0x124>(s);   // row_ror:4
    s += dpp_f32<0x128>(s);   // row_ror:8  -> 16-lane row sum
    float r0 = __int_as_float(__builtin_amdgcn_readlane(__float_as_int(s), 0));
    float r1 = __int_as_float(__builtin_amdgcn_readlane(__float_as_int(s), 16));
    float r2 = __int_as_float(__builtin_amdgcn_readlane(__float_as_int(s), 32));
    float r3 = __int_as_float(__builtin_amdgcn_readlane(__float_as_int(s), 48));
    return (r0 + r1) + (r2 + r3);
}

// monotonic f64 -> u64 key (order-preserving)
__device__ __forceinline__ unsigned long long f64key(double d) {
    unsigned long long u = (unsigned long long)__double_as_longlong(d);
    return u ^ ((unsigned long long)((long long)u >> 63) | 0x8000000000000000ull);
}

// monotonic f32 -> u32 key (order-preserving)
__device__ __forceinline__ unsigned f32key(float f) {
    unsigned u = (unsigned)__float_as_int(f);
    return u ^ ((unsigned)((int)u >> 31) | 0x80000000u);
}

// ---------------------------------------------------------------------------
// Kernel 1: block-tiled softmax + cost gather + per-block row-min keys.
// vs round-11: 2-row software pipeline per wave + DPP sum reduce (sum-order
// change only -- validated perturbation class). Transpose write + part-key
// logic byte-identical to round 7/11.
// ---------------------------------------------------------------------------
__global__ __launch_bounds__(512) void softmax_cost_kernel(
    const float* __restrict__ pred, const int* __restrict__ tgt,
    float* __restrict__ cost, unsigned long long* __restrict__ part)
{
    int b = blockIdx.x / QB, qblk = blockIdx.x % QB;
    int wave = threadIdx.x >> 6, lane = threadIdx.x & 63;
    int qcnt = (qblk == QB - 1) ? (NQ - 64 * (QB - 1)) : 64;   // 4 or 64

    __shared__ float tile[64][65];
    int lab = tgt[b * NT + lane];                 // lane = target t

    for (int qloc = wave; qloc < qcnt; qloc += 16) {
        int q0 = qblk * 64 + qloc;
        bool two = (qloc + 8) < qcnt;
        int q1 = qblk * 64 + (two ? qloc + 8 : qloc);
        const float* rpA = pred + ((size_t)b * NQ + q0) * NC;
        const float* rpB = pred + ((size_t)b * NQ + q1) * NC;

        float xlA = rpA[lab];                     // issue gathers early
        float xlB = rpB[lab];
        float sA = 0.0f, sB = 0.0f;
#pragma unroll
        for (int k = 0; k < 19; ++k) {
            int idx = lane + (k << 6);
            if (idx < NC) {
                float va = rpA[idx];              // both rows' loads in flight
                float vb = rpB[idx];
                sA += __expf(va);
                sB += __expf(vb);
            }
        }
        sA = wave_sum(sA);
        sB = wave_sum(sB);

        tile[lane][qloc] = -(__expf(xlA) / sA);   // lane = target t
        if (two) tile[lane][qloc + 8] = -(__expf(xlB) / sB);
    }
    __syncthreads();

    // coalesced write + per-row block min (lane = q)
    for (int t = wave; t < NT; t += 8) {
        float v = (lane < qcnt) ? tile[t][lane] : INFINITY;
        int q = qblk * 64 + lane;
        if (lane < qcnt)
            cost[((size_t)b * NT + t) * NQ + q] = v;

        unsigned long long key =
            ((unsigned long long)f32key(v) << 32) | (unsigned)q;
        key = umin64(key, dpp_u64<0xB1>(key));    // quad_perm [1,0,3,2]
        key = umin64(key, dpp_u64<0x4E>(key));    // quad_perm [2,3,0,1]
        key = umin64(key, dpp_u64<0x124>(key));   // row_ror:4
        key = umin64(key, dpp_u64<0x128>(key));   // row_ror:8
        unsigned long long kmin =
            umin64(umin64(rl_u64(key, 0),  rl_u64(key, 16)),
                   umin64(rl_u64(key, 32), rl_u64(key, 48)));
        if (lane == 0) part[((size_t)b * NT + t) * QB + qblk] = kmin;
    }
}

// ---------------------------------------------------------------------------
// Kernel 2: exact JV -- VERBATIM round-11 PASSED kernel. Waves 1-7: warm the
// local XCD L2 with the batch's cost block, then exit. Wave 0: barrier-free
// single-wave f64 solver (shuffle dup-detect greedy init, deferred bit-exact
// dual replay).
// ---------------------------------------------------------------------------
__global__ __launch_bounds__(512) void jv_kernel(
    const float* __restrict__ cost,
    const unsigned long long* __restrict__ part, int* __restrict__ out)
{
    const int b    = blockIdx.x;
    const int wave = threadIdx.x >> 6;
    const int lane = threadIdx.x & 63;
    const float* a = cost + (size_t)b * NT * NQ;

    // ---------------- prefetch crew: warm local L2, then exit -------------
    if (wave != 0) {
        const float4* a4 = (const float4*)a;      // 14400 float4
        float acc = 0.0f;
        int base = (wave - 1) * 64 + lane;        // [0, 448)
        for (int g = 0; g < 5; ++g) {
            float4 v[8];
#pragma unroll
            for (int t = 0; t < 8; ++t) {
                int idx = base + g * 3584 + t * 448;
                v[t] = (idx < NT * NQ / 4) ? a4[idx] : make_float4(0, 0, 0, 0);
            }
#pragma unroll
            for (int t = 0; t < 8; ++t)
                acc += v[t].x + v[t].y + v[t].z + v[t].w;
        }
        asm volatile("" :: "v"(acc));             // sink (prevent DCE)
        return;
    }

    // -------- wave 0: single-wave exact JV (round-9/11 PASSED solver) -----
    __shared__ double u[NT + 1];
    __shared__ double deltas[NT + 8];
    __shared__ int    p[NQ + 1];
    __shared__ int    way[NQ + 1];

    for (int j = lane; j <= NQ; j += 64) p[j] = 0;

    double vv[NCH];
    double minv[NCH];
    float  rA[NCH];
    int    wy[NCH];
    int    sj[NCH];

#pragma unroll
    for (int c = 0; c < NCH; ++c) vv[c] = 0.0;

    const unsigned invalid = (lane < 4) ? 0u : (1u << 14);

#define GLOAD_TO(DST, I0)                                             \
    do {                                                              \
        const float* ar_ = a + (size_t)((I0) - 1) * NQ;               \
        _Pragma("unroll")                                             \
        for (int c_ = 0; c_ < 14; ++c_) DST[c_] = ar_[c_ * 64 + lane];\
        DST[14] = (lane < 4) ? ar_[896 + lane] : 0.0f;                \
    } while (0)

    // ---- Phase A: reduce parts, greedy init (shuffle dup-detect) ----
    const unsigned long long* pp = part + ((size_t)b * NT + lane) * QB;
    unsigned long long rm = pp[0];
#pragma unroll
    for (int k = 1; k < QB; ++k) rm = umin64(rm, pp[k]);

    unsigned k32 = (unsigned)(rm >> 32);
    unsigned ubits = (k32 & 0x80000000u) ? (k32 ^ 0x80000000u) : ~k32;  // inverse f32key
    float mval = __int_as_float((int)ubits);
    int col = (int)(rm & 0xFFFFFFFFu) + 1;           // 1-based argmin column

    u[lane + 1] = (double)mval;                      // u[t] = rowmin (JV-legal)
    if (lane == 0) u[0] = 0.0;

    int dup = 0;
    for (int t2 = 0; t2 < NT; ++t2) {
        int c2 = __shfl(col, t2);
        if (t2 < lane && c2 == col) dup = 1;         // earlier row took my column
    }
    bool m0 = !dup;
    if (m0) p[col] = lane + 1;                       // matched cols are distinct
    unsigned long long matched_rows = __ballot(m0);

    // ---- Phase B: Dijkstra for unmatched rows (f64, bit-exact replay) ----
    unsigned long long um = ~matched_rows;
    while (um) {
        int i = __ffsll((long long)um);              // row 1..64
        um &= um - 1;

        GLOAD_TO(rA, i);
        if (lane == 0) p[0] = i;
#pragma unroll
        for (int c = 0; c < NCH; ++c) { minv[c] = INFINITY; wy[c] = 0; }
        unsigned joined = 0;
        double pdelta = 0.0;
        double ui0 = u[i];
        int j0 = 0, K = 0;

        for (int k = 1; k <= NT + 2; ++k) {
            K = k;
            unsigned fm = ~(joined | invalid);
            double tv[16]; int tj[16];
#pragma unroll
            for (int c = 0; c < NCH; ++c) {
                double m   = minv[c] - pdelta;           // deferred subtract
                double cur = (double)rA[c] - ui0 - vv[c];
                bool live = (fm >> c) & 1;
                if (live && (cur < m)) wy[c] = j0;
                if (cur < m) m = cur;                    // joined drift never read
                minv[c] = m;
                tv[c] = live ? m : INFINITY;
                tj[c] = 1 + c * 64 + lane;
            }
            tv[15] = INFINITY; tj[15] = 0x7fffffff;
            // ordered adjacent-pair tree (strict < keeps smaller j on ties)
#pragma unroll
            for (int w = 16; w > 1; w >>= 1)
#pragma unroll
                for (int t = 0; t < (w >> 1); ++t) {
                    if (tv[2 * t + 1] < tv[2 * t]) { tv[t] = tv[2 * t + 1]; tj[t] = tj[2 * t + 1]; }
                    else                           { tv[t] = tv[2 * t];     tj[t] = tj[2 * t]; }
                }
            double bestv = tv[0];
            int    bestj = tj[0];

            // speculative p/u reads (latency hidden under the reduce)
            int bjc = (bestj <= NQ) ? bestj : 0;
            int ppj_spec = p[bjc];
            double u_spec = u[ppj_spec];

            unsigned long long key = f64key(bestv);
            unsigned long long kk = key;
            kk = umin64(kk, dpp_u64<0xB1>(kk));
            kk = umin64(kk, dpp_u64<0x4E>(kk));
            kk = umin64(kk, dpp_u64<0x124>(kk));
            kk = umin64(kk, dpp_u64<0x128>(kk));
            unsigned long long kmin =
                umin64(umin64(rl_u64(kk, 0),  rl_u64(kk, 16)),
                       umin64(rl_u64(kk, 32), rl_u64(kk, 48)));
            unsigned long long mask = __ballot(key == kmin);
            int wl = __ffsll((long long)mask) - 1;
            int j1 = __builtin_amdgcn_readlane(bestj, wl);
            int lane1 = wl;
            if (__popcll(mask) > 1) {                    // exact tie: smallest j
                unsigned long long mm = mask & (mask - 1);
                while (mm) {
                    int l2 = __ffsll((long long)mm) - 1;
                    int j2 = __builtin_amdgcn_readlane(bestj, l2);
                    if (j2 < j1) { j1 = j2; lane1 = l2; }
                    mm &= mm - 1;
                }
            }
            double delta = __longlong_as_double(
                (long long)rl_u64((unsigned long long)__double_as_longlong(bestv), wl));

            if (lane == 0) deltas[k] = delta;
            pdelta = delta;

            int och = (j1 - 1) >> 6, oln = (j1 - 1) & 63;
#pragma unroll
            for (int c = 0; c < NCH; ++c)
                if (och == c && lane == oln) { joined |= (1u << c); sj[c] = k + 1; }

            int ppj1 = __builtin_amdgcn_readlane(ppj_spec, lane1);
            j0 = j1;
            if (ppj1 == 0) break;                        // augmenting path found

            ui0 = __longlong_as_double((long long)rl_u64(
                (unsigned long long)__double_as_longlong(u_spec), lane1));
            GLOAD_TO(rA, ppj1);
        }

        // ---- phase epilogue (single wave: LDS ops program-ordered) ----
#pragma unroll
        for (int c = 0; c < NCH; ++c) {
            int j = 1 + c * 64 + lane;
            if (j <= NQ) way[j] = wy[c];
        }

#pragma unroll
        for (int c = 0; c < NCH; ++c) {
            if (joined & (1u << c)) {
                int s = sj[c];
                if (s <= K) {
                    int j = 1 + c * 64 + lane;
                    double vacc = vv[c];
                    for (int k2 = s; k2 <= K; ++k2) vacc -= deltas[k2];
                    vv[c] = vacc;
                    int pj = p[j];                       // pre-augmentation p
                    double ua = u[pj];
                    for (int k2 = s; k2 <= K; ++k2) ua += deltas[k2];
                    u[pj] = ua;
                }
            }
        }
        if (lane == 0) {
            double ua = u[i];
            for (int k2 = 1; k2 <= K; ++k2) ua += deltas[k2];
            u[i] = ua;
        }

        if (lane == 0) {                                 // augment
            int jj = j0;
            for (int g = 0; g < NT + 4 && jj != 0; ++g) {
                int jn = way[jj];
                p[jj] = p[jn];
                jj = jn;
            }
        }
    }
#undef GLOAD_TO

    // ---- compaction ----
    int base_cnt = 0;
    for (int c = 0; c < NCH; ++c) {
        int j = 1 + c * 64 + lane;
        bool matched = (j <= NQ) && (p[j] != 0);
        unsigned long long mask = __ballot(matched);
        int rank = base_cnt + __popcll(mask & ((1ull << lane) - 1ull));
        if (matched) {
            out[b * NT + rank]           = j - 1;     // rows: query index
            out[BS * NT + b * NT + rank] = p[j] - 1;  // cols: target index
        }
        base_cnt += __popcll(mask);
    }
}

extern "C" void kernel_launch(void* const* d_in, const int* in_sizes, int n_in,
                              void* d_out, int out_size, void* d_ws, size_t ws_size,
                              hipStream_t stream) {
    const float* pred = (const float*)d_in[0];  // [32,900,1203] f32
    const int*   tgt  = (const int*)d_in[1];    // [32,64] int
    int*         out  = (int*)d_out;            // [2][32][64] int32

    char* ws = (char*)d_ws;
    float* cost = (float*)ws;                                      // 7,372,800 B
    unsigned long long* part =
        (unsigned long long*)(ws + (size_t)BS * NT * NQ * 4);      // 245,760 B

    softmax_cost_kernel<<<BS * QB, 512, 0, stream>>>(pred, tgt, cost, part);
    jv_kernel<<<BS, 512, 0, stream>>>(cost, part, out);
}